// Round 23
// baseline (824.203 us; speedup 1.0000x reference)
//
#include <hip/hip_runtime.h>
#include <stdint.h>

typedef _Float16 f16;
typedef _Float16 f16x8 __attribute__((ext_vector_type(8)));
typedef float    f32x4 __attribute__((ext_vector_type(4)));
typedef unsigned long long u64;

#define L_    128
#define B_    64
#define E_    512
#define H_    512
#define G3    1536   // 3*H
#define NCOL  3072   // 2*3H
#define IBSZ  16384  // one inbox buffer: 16 rows x 512 f16

__device__ __forceinline__ float sigm_(float x){ return 1.0f/(1.0f + __expf(-x)); }
__device__ __forceinline__ float tanh_(float x){ return 1.0f - 2.0f/(__expf(2.0f*x) + 1.0f); }

// ---------------- P1: embedding gather, f32 -> f16 (+ flag zeroing in block 0) ----------------
__global__ __launch_bounds__(256) void k_embed(const int* __restrict__ xs,
                                               const float* __restrict__ emb,
                                               f16* __restrict__ Xe,
                                               uint4* __restrict__ flags4){
  if (blockIdx.x == 0){
    flags4[threadIdx.x]       = make_uint4(0,0,0,0);   // 4KB
    flags4[256 + threadIdx.x] = make_uint4(0,0,0,0);   // 8KB total (256 wave-flags x 32B)
  }
  int row = blockIdx.x*2 + (threadIdx.x >> 7);       // 2 rows / block
  int c   = (threadIdx.x & 127) * 4;
  int idx = xs[row];
  float4 v = *(const float4*)(emb + (size_t)idx*E_ + c);
  union { f16 h[4]; uint2 u; } p;
  p.h[0] = (f16)v.x; p.h[1] = (f16)v.y; p.h[2] = (f16)v.z; p.h[3] = (f16)v.w;
  *(uint2*)(Xe + (size_t)row*E_ + c) = p.u;
}

// ---------------- P2: transpose+cast 4 weight matrices (512x1536 f32 -> 1536x512 f16) ----------------
__global__ __launch_bounds__(256) void k_transpose(const float* __restrict__ Wx_f, const float* __restrict__ Wx_b,
                                                   const float* __restrict__ Wh_f, const float* __restrict__ Wh_b,
                                                   f16* __restrict__ WxT, f16* __restrict__ WhT){
  int mat = blockIdx.z;
  const float* src = mat==0 ? Wx_f : mat==1 ? Wx_b : mat==2 ? Wh_f : Wh_b;
  f16* dst = (mat < 2) ? (WxT + (size_t)mat*G3*E_) : (WhT + (size_t)(mat-2)*G3*H_);
  int n0 = blockIdx.x*64, k0 = blockIdx.y*64;
  __shared__ f16 tile[64][65];
  int tid = threadIdx.x;
  for (int i=0;i<16;i++){
    int r = i*4 + (tid>>6);      // k
    int c = tid & 63;            // n
    tile[r][c] = (f16)src[(size_t)(k0+r)*G3 + n0 + c];
  }
  __syncthreads();
  for (int i=0;i<16;i++){
    int n = i*4 + (tid>>6);
    int k = tid & 63;
    dst[(size_t)(n0+n)*512 + k0 + k] = tile[k][n];
  }
}

// ---------------- G: xw2[t][col][b] = (Xe @ WxT^T + bias), f16 MFMA 128x128 tiles ----------------
__global__ __launch_bounds__(256) void k_gemm(const f16* __restrict__ Xe, const f16* __restrict__ WxT,
                                              const float* __restrict__ bf, const float* __restrict__ bb,
                                              f16* __restrict__ xw2){
  __shared__ __align__(16) f16 sA[128*32];
  __shared__ __align__(16) f16 sB[128*32];
  const int tid = threadIdx.x;
  const int l = tid & 63, w = tid >> 6;
  const int wr = w >> 1, wc = w & 1;
  const int m0 = blockIdx.y*128, n0 = blockIdx.x*128;
  const int rl = l & 15, sg = l >> 4;
  f32x4 acc[4][4] = {};
  for (int kk=0; kk<16; ++kk){
    __syncthreads();
    for (int i=0;i<2;i++){
      int c = i*256 + tid; int row = c>>2, s = c&3;
      int sw = s ^ ((row>>1)&3);                       // bank-swizzle for 64B rows
      *(uint4*)&sA[row*32 + sw*8] = *(const uint4*)(Xe  + (size_t)(m0+row)*512 + kk*32 + s*8);
      *(uint4*)&sB[row*32 + sw*8] = *(const uint4*)(WxT + (size_t)(n0+row)*512 + kk*32 + s*8);
    }
    __syncthreads();
    f16x8 a[4], b[4];
    for (int mi=0;mi<4;mi++){ int m=(wr*4+mi)*16+rl; a[mi] = *(const f16x8*)&sA[m*32 + ((sg^((m>>1)&3))*8)]; }
    for (int nj=0;nj<4;nj++){ int n=(wc*4+nj)*16+rl; b[nj] = *(const f16x8*)&sB[n*32 + ((sg^((n>>1)&3))*8)]; }
    for (int mi=0;mi<4;mi++)
      for (int nj=0;nj<4;nj++)
        acc[mi][nj] = __builtin_amdgcn_mfma_f32_16x16x32_f16(a[mi], b[nj], acc[mi][nj], 0,0,0);
  }
  // epilogue: write transposed layout xw2[t][n][b] (b fastest, 64 per (t,n))
  for (int nj=0;nj<4;nj++){
    int n = n0 + (wc*4+nj)*16 + rl;
    float bias = (n < G3) ? bf[n] : bb[n-G3];
    for (int mi=0;mi<4;mi++){
      int sub = (wr*4+mi)*16 + sg*4;       // row within 128-tile
      int t   = (m0 + sub) >> 6;
      int b0  = sub & 63;
      union { f16 h[4]; uint2 u; } p;
      for (int r=0;r<4;r++) p.h[r] = (f16)(acc[mi][nj][r] + bias);
      *(uint2*)(xw2 + ((size_t)t*NCOL + n)*B_ + b0) = p.u;
    }
  }
}

// ---------------- F: fill inbox ring with sentinel (runs AFTER k_gemm; overlays dead Xe) ----------------
__global__ __launch_bounds__(256) void k_fill(uint4* p){
  p[(size_t)blockIdx.x*256 + threadIdx.x] = make_uint4(~0u,~0u,~0u,~0u);   // 2048x256x16B = 8MB
}

// ---------------- S: bidirectional GRU scan — inbox/sentinel protocol ----------------
// grid = 128 x 128thr (rd16 shape): dir=bx>>6, m=(bx>>4)&3, n=bx&15; group (dir,m)=16 blocks.
// Each block has a PRIVATE 4-deep inbox ring (4 x 16KB). Producers write their 1KB slice
// into all 16 members' inboxes + store a per-WAVE flag immediately (no drain — flag may
// race data). Consumers spin flags, bulk-load their own inbox, then VALIDATE each 8B
// granule against the sentinel (~0ull; h in (-1,1) can never be NaN) and retry stragglers.
// Consumed buffers are restored to sentinel LAZILY next step (4-deep ring gives 3 steps
// of slack; the ~free pre-publish vmcnt(0) orders restore-before-republish). This removes
// the publish-ack RTT and merges flag-observe with data-load: ~2 far-RTTs/step vs rd22's 3.
__global__ __launch_bounds__(128, 1) void k_scan(const f16* __restrict__ xw2, const f16* __restrict__ WhT,
                                                 char* __restrict__ inb, const float* __restrict__ mask,
                                                 float* __restrict__ out, unsigned* __restrict__ flags){
  const int dir = blockIdx.x >> 6;
  const int m   = (blockIdx.x >> 4) & 3;
  const int n   = blockIdx.x & 15;
  const int gidx = dir*4 + m;                 // sync group (8 total)
  __shared__ __align__(16) f16 sX[2*16*16];   // 1KB: per-wave 16x16 transpose scratch
  const int tid = threadIdx.x, l = tid & 63, wv = tid >> 6;   // wv in {0,1}
  const int fl = l & 15, sg = l >> 4;
  const int fbase = n*32 + wv*16;             // this wave's 16 features (within 512)
  // one-time: 48 B-fragments (Wh cols for z,r,h of our features) direct from global, pinned
  f16x8 pz[16], pr[16], ph[16];
  {
    const f16* wb = WhT + (size_t)dir*G3*512;
    #pragma unroll
    for (int kk=0;kk<16;kk++){
      int ko = kk*32 + sg*8;
      pz[kk] = *(const f16x8*)(wb + (size_t)(       fbase + fl)*512 + ko);
      pr[kk] = *(const f16x8*)(wb + (size_t)( 512 + fbase + fl)*512 + ko);
      ph[kk] = *(const f16x8*)(wb + (size_t)(1024 + fbase + fl)*512 + ko);
    }
  }
  #pragma unroll
  for (int kk=0;kk<16;kk++){
    asm volatile("" : "+v"(pz[kk]));
    asm volatile("" : "+v"(pr[kk]));
    asm volatile("" : "+v"(ph[kk]));
  }
  float hstate[4] = {0.f,0.f,0.f,0.f};
  float* out2 = out + (size_t)L_*B_*1024;
  const int mb = m*16 + sg*4;                 // absolute batch base of this lane's C rows
  // per-WAVE flags: slot (n*2+wv)*8+gidx, 32B spacing; group's 32 wave-flags
  unsigned* myflag = flags + ((size_t)(n*2 + wv)*8 + gidx)*8;
  const unsigned* pollp = flags + ((size_t)(l & 31)*8 + gidx)*8;
  f16* const sXw = &sX[wv*256];               // this wave's 512B transpose tile
  const int prow = l >> 2, pf = (l & 3)*4;    // publish mapping after transpose
  char* const ginb = inb + (size_t)(gidx*16)*4*IBSZ;   // group inbox base
  char* const myinb = ginb + (size_t)n*4*IBSZ;         // this block's 4-buffer ring

  for (int ti=0; ti<128; ++ti){
    const int t = dir ? (127 - ti) : ti;
    // ---- lazy restore of the buffer consumed LAST step (3 steps of slack) ----
    if (ti >= 2){
      u64* rb = (u64*)(myinb + (size_t)((ti-1)&3)*IBSZ);
      #pragma unroll
      for (int k2=0;k2<8;k2++)
        __hip_atomic_store(rb + tid + 128*k2, ~0ull, __ATOMIC_RELAXED, __HIP_MEMORY_SCOPE_AGENT);
    }
    // ---- prefetch xw gates + mask (independent of h; hides under poll) ----
    size_t xb = ((size_t)t*NCOL + dir*G3 + fbase + fl)*B_ + mb;
    union { uint2 u; f16 h[4]; } xzv, xrv, xhv;
    xzv.u = *(const uint2*)(xw2 + xb);
    xrv.u = *(const uint2*)(xw2 + xb + (size_t)512*B_);
    xhv.u = *(const uint2*)(xw2 + xb + (size_t)1024*B_);
    float4 mv4 = *(const float4*)(mask + t*B_ + mb);
    // ---- wait (flag hint) -> load own inbox -> sentinel-validate -> MFMA ----
    f32x4 az = {0,0,0,0}, ar = {0,0,0,0}, ah = {0,0,0,0};
    if (ti){
      unsigned tgt = (unsigned)ti;
      while (true){
        unsigned f = __hip_atomic_load(pollp, __ATOMIC_RELAXED, __HIP_MEMORY_SCOPE_AGENT);
        if (__all((int)(f >= tgt))) break;
      }
      const u64* ib = (const u64*)(myinb + (size_t)(ti&3)*IBSZ) + (size_t)fl*128;
      u64 q[32];
      #pragma unroll
      for (int kk=0;kk<16;kk++){
        int j = kk*8 + sg*2;                // == (kk*4+sg)*2
        q[2*kk  ] = __hip_atomic_load(ib + j,     __ATOMIC_RELAXED, __HIP_MEMORY_SCOPE_AGENT);
        q[2*kk+1] = __hip_atomic_load(ib + j + 1, __ATOMIC_RELAXED, __HIP_MEMORY_SCOPE_AGENT);
      }
      while (true){
        int ok = 1;
        #pragma unroll
        for (int i=0;i<32;i++) ok &= (int)(q[i] != ~0ull);
        if (__all(ok)) break;
        #pragma unroll
        for (int kk=0;kk<16;kk++){
          int j = kk*8 + sg*2;
          if (q[2*kk  ] == ~0ull) q[2*kk  ] = __hip_atomic_load(ib + j,     __ATOMIC_RELAXED, __HIP_MEMORY_SCOPE_AGENT);
          if (q[2*kk+1] == ~0ull) q[2*kk+1] = __hip_atomic_load(ib + j + 1, __ATOMIC_RELAXED, __HIP_MEMORY_SCOPE_AGENT);
        }
      }
      __syncthreads();   // both waves finished reading buf ti&3 (gates next step's restore)
      #pragma unroll
      for (int kk=0;kk<16;kk++){
        union { u64 d[2]; f16x8 h; } a;
        a.d[0] = q[2*kk]; a.d[1] = q[2*kk+1];
        az = __builtin_amdgcn_mfma_f32_16x16x32_f16(a.h, pz[kk], az, 0,0,0);
        ar = __builtin_amdgcn_mfma_f32_16x16x32_f16(a.h, pr[kk], ar, 0,0,0);
        ah = __builtin_amdgcn_mfma_f32_16x16x32_f16(a.h, ph[kk], ah, 0,0,0);
      }
    }
    // ---- gates + state update (lane = feature fbase+fl, batch rows mb..mb+3) ----
    #pragma unroll
    for (int r=0;r<4;r++){
      float z  = sigm_((float)xzv.h[r] + az[r]);
      float rr = sigm_((float)xrv.h[r] + ar[r]);
      float ht = tanh_((float)xhv.h[r] + rr*ah[r]);
      float mv = (&mv4.x)[r];
      float hn = (1.0f - z)*hstate[r] + z*ht;
      hn = mv*hn + (1.0f - mv)*hstate[r];
      hstate[r] = hn;
    }
    // ---- publish: LDS transpose -> vmcnt(0) (orders restores; ~free) -> 16 inbox copies -> wave flag ----
    if (ti < 127){
      #pragma unroll
      for (int r=0;r<4;r++) sXw[(sg*4 + r)*16 + fl] = (f16)hstate[r];
      asm volatile("s_waitcnt lgkmcnt(0)" ::: "memory");   // wave-local ds ordering
      u64 v = *(const u64*)&sXw[prow*16 + pf];
      asm volatile("s_waitcnt vmcnt(0)" ::: "memory");     // restores/loads drained (long done)
      const size_t gofs = (size_t)prow*128 + ((fbase + pf) >> 2);
      const size_t bofs = (size_t)((ti+1)&3)*IBSZ;
      #pragma unroll
      for (int c=0;c<16;c++){
        int cc = (n + c) & 15;
        u64* dst = (u64*)(ginb + (size_t)cc*4*IBSZ + bofs) + gofs;
        __hip_atomic_store(dst, v, __ATOMIC_RELAXED, __HIP_MEMORY_SCOPE_AGENT);
      }
      if (l == 0)
        __hip_atomic_store(myflag, (unsigned)(ti+1),
                           __ATOMIC_RELAXED, __HIP_MEMORY_SCOPE_AGENT);
    }
    // ---- outputs (off the critical path) ----
    #pragma unroll
    for (int r=0;r<4;r++)
      out[((size_t)(t*B_ + mb + r))*1024 + dir*512 + fbase + fl] = hstate[r];
    if (dir==1 && t==0){
      #pragma unroll
      for (int r=0;r<4;r++)
        out2[(size_t)(mb + r)*512 + fbase + fl] = hstate[r];
    }
  }
}

extern "C" void kernel_launch(void* const* d_in, const int* in_sizes, int n_in,
                              void* d_out, int out_size, void* d_ws, size_t ws_size,
                              hipStream_t stream){
  const int*   xs      = (const int*)  d_in[0];
  const float* xs_mask = (const float*)d_in[1];
  const float* emb     = (const float*)d_in[2];
  const float* Wx_f    = (const float*)d_in[3];
  const float* Wh_f    = (const float*)d_in[4];
  const float* b_f     = (const float*)d_in[5];
  const float* Wx_b    = (const float*)d_in[6];
  const float* Wh_b    = (const float*)d_in[7];
  const float* b_b     = (const float*)d_in[8];

  char* w = (char*)d_ws;
  f16*      Xe    = (f16*)(w);                  //  8,388,608 B (dead after k_gemm)
  char*     inbox = w;                          //  8,388,608 B inbox ring (overlays Xe)
  f16*      WxT   = (f16*)(w + 8388608);        //  3,145,728 B
  f16*      WhT   = (f16*)(w + 11534336);       //  3,145,728 B
  f16*      xw2   = (f16*)(w + 14680064);       // 50,331,648 B
  unsigned* flags = (unsigned*)(w + 65273856);  //  8,192 B (256 wave-flags x 32B)
  float*    out   = (float*)d_out;

  k_embed    <<<dim3(4096),    dim3(256), 0, stream>>>(xs, emb, Xe, (uint4*)flags);
  k_transpose<<<dim3(24,8,4),  dim3(256), 0, stream>>>(Wx_f, Wx_b, Wh_f, Wh_b, WxT, WhT);
  k_gemm     <<<dim3(24,64),   dim3(256), 0, stream>>>(Xe, WxT, b_f, b_b, xw2);
  k_fill     <<<dim3(2048),    dim3(256), 0, stream>>>((uint4*)inbox);
  k_scan     <<<dim3(128),     dim3(128), 0, stream>>>(xw2, WhT, inbox, xs_mask, out, flags);
}